// Round 1
// baseline (1026.235 us; speedup 1.0000x reference)
//
#include <hip/hip_runtime.h>

typedef __attribute__((ext_vector_type(8))) short short8;
typedef __attribute__((ext_vector_type(4))) float f32x4;
typedef __attribute__((ext_vector_type(8))) unsigned short ushort8;

__device__ __forceinline__ unsigned short f2bf(float f) {
  union { float f; unsigned u; } v; v.f = f;
  unsigned u = v.u;
  u += 0x7fffu + ((u >> 16) & 1u);
  return (unsigned short)(u >> 16);
}
__device__ __forceinline__ float sigm(float x) { return 1.f / (1.f + __expf(-x)); }

// ---------------------------------------------------------------------------
// Prep: build bf16 transposed/permuted weights, zero state buffers.
// WcombT: (2048 rows n', 800 cols k) bf16. n' = j*4+gate  (orig col n = gate*512+j)
//         k<257 -> W_lstm[k][n]; 288<=k<800 -> U_lstm[k-288][n]; else 0.
// Wk2T:   (320 rows n, 512 cols k) bf16. n<256->W_key, 256->W_g, 257..260->W_y, else 0
// WencT:  (128 rows n, 1024 cols k) bf16 = W_enc^T
// ---------------------------------------------------------------------------
__global__ void k_prep(const float* __restrict__ W_lstm, const float* __restrict__ U_lstm,
                       const float* __restrict__ W_enc, const float* __restrict__ W_key,
                       const float* __restrict__ W_g, const float* __restrict__ W_y,
                       const float* __restrict__ b_key, const float* __restrict__ b_g,
                       const float* __restrict__ b_y,
                       unsigned short* __restrict__ WcombT, unsigned short* __restrict__ Wk2T,
                       unsigned short* __restrict__ WencT, float* __restrict__ bias2,
                       unsigned short* __restrict__ xinA, unsigned short* __restrict__ xinB,
                       float* __restrict__ h, float* __restrict__ z_full) {
  const int N1 = 2048 * 800, N2 = 320 * 512, N3 = 128 * 1024, N4 = 320,
            N5 = 512 * 800, N7 = 512 * 512, N8 = 512 * 128;
  int i = blockIdx.x * 256 + threadIdx.x;
  if (i < N1) {
    int np = i / 800, k = i - np * 800;
    int j = np >> 2, gate = np & 3, n = gate * 512 + j;
    float v = 0.f;
    if (k < 257) v = W_lstm[k * 2048 + n];
    else if (k >= 288) v = U_lstm[(k - 288) * 2048 + n];
    WcombT[i] = f2bf(v);
    return;
  }
  i -= N1;
  if (i < N2) {
    int n = i / 512, k = i - n * 512;
    float v = 0.f;
    if (n < 256) v = W_key[k * 256 + n];
    else if (n == 256) v = W_g[k];
    else if (n < 261) v = W_y[k * 4 + (n - 257)];
    Wk2T[i] = f2bf(v);
    return;
  }
  i -= N2;
  if (i < N3) {
    int n = i / 1024, k = i - n * 1024;
    WencT[i] = f2bf(W_enc[k * 128 + n]);
    return;
  }
  i -= N3;
  if (i < N4) {
    float v = (i < 256) ? b_key[i] : (i == 256 ? b_g[0] : (i < 261 ? b_y[i - 257] : 0.f));
    bias2[i] = v;
    return;
  }
  i -= N4;
  if (i < N5) { xinA[i] = 0; return; }
  i -= N5;
  if (i < N5) { xinB[i] = 0; return; }
  i -= N5;
  if (i < N7) { h[i] = 0.f; return; }
  i -= N7;
  if (i < N8) {
    int b = i >> 7, z = i & 127;
    z_full[(b * 33 + 32) * 128 + z] = 0.f;  // null slot
  }
}

// ---------------------------------------------------------------------------
// Encoder GEMM: z = relu(x @ W_enc + b_enc). A = x f32 (16384,1024) converted
// on the fly; B = WencT bf16 (128,1024). Out zbuf (16384,128) f32.
// Tile 64x64, BK=32, 256 threads (4 waves, 2x2 of 32x32).
// ---------------------------------------------------------------------------
__global__ __launch_bounds__(256) void k_enc(const float* __restrict__ x,
                                             const unsigned short* __restrict__ WencT,
                                             const float* __restrict__ b_enc,
                                             float* __restrict__ zbuf) {
  __shared__ __align__(16) unsigned short As[64 * 32];
  __shared__ __align__(16) unsigned short Bs[64 * 32];
  int tid = threadIdx.x;
  int n0 = blockIdx.x * 64;
  int m0 = blockIdx.y * 64;
  int lane = tid & 63, wid = tid >> 6;
  int wm = (wid >> 1) * 32, wn = (wid & 1) * 32;
  int q = lane >> 4, r = lane & 15;
  int ldrow = tid >> 2, ldc = (tid & 3) * 8;
  const float4* Ag = reinterpret_cast<const float4*>(x + (size_t)(m0 + ldrow) * 1024);
  const uint4* Bg = reinterpret_cast<const uint4*>(WencT + (size_t)(n0 + ldrow) * 1024);
  f32x4 acc[2][2] = {};
  for (int kk = 0; kk < 32; ++kk) {
    int k0 = kk * 32;
    float4 v0 = Ag[(k0 + ldc) >> 2];
    float4 v1 = Ag[((k0 + ldc) >> 2) + 1];
    ushort8 t8;
    t8[0] = f2bf(v0.x); t8[1] = f2bf(v0.y); t8[2] = f2bf(v0.z); t8[3] = f2bf(v0.w);
    t8[4] = f2bf(v1.x); t8[5] = f2bf(v1.y); t8[6] = f2bf(v1.z); t8[7] = f2bf(v1.w);
    *reinterpret_cast<ushort8*>(&As[ldrow * 32 + ldc]) = t8;
    *reinterpret_cast<uint4*>(&Bs[ldrow * 32 + ldc]) = Bg[(k0 + ldc) >> 3];
    __syncthreads();
    short8 a0 = *reinterpret_cast<const short8*>(&As[(wm + r) * 32 + q * 8]);
    short8 a1 = *reinterpret_cast<const short8*>(&As[(wm + 16 + r) * 32 + q * 8]);
    short8 b0 = *reinterpret_cast<const short8*>(&Bs[(wn + r) * 32 + q * 8]);
    short8 b1 = *reinterpret_cast<const short8*>(&Bs[(wn + 16 + r) * 32 + q * 8]);
    acc[0][0] = __builtin_amdgcn_mfma_f32_16x16x32_bf16(a0, b0, acc[0][0], 0, 0, 0);
    acc[0][1] = __builtin_amdgcn_mfma_f32_16x16x32_bf16(a0, b1, acc[0][1], 0, 0, 0);
    acc[1][0] = __builtin_amdgcn_mfma_f32_16x16x32_bf16(a1, b0, acc[1][0], 0, 0, 0);
    acc[1][1] = __builtin_amdgcn_mfma_f32_16x16x32_bf16(a1, b1, acc[1][1], 0, 0, 0);
    __syncthreads();
  }
  for (int mt = 0; mt < 2; ++mt)
    for (int nt = 0; nt < 2; ++nt)
      for (int e = 0; e < 4; ++e) {
        int row = m0 + wm + mt * 16 + q * 4 + e;
        int col = n0 + wn + nt * 16 + r;
        zbuf[(size_t)row * 128 + col] = fmaxf(acc[mt][nt][e] + b_enc[col], 0.f);
      }
}

// ---------------------------------------------------------------------------
// LayerNorm over the BATCH axis per (t,z). Block = (t, 16 z's); 256 threads =
// 16 b-groups x 16 z. Writes z_full[(b*33+t)*128+z].
// ---------------------------------------------------------------------------
__global__ __launch_bounds__(256) void k_ln(const float* __restrict__ zbuf,
                                            const float* __restrict__ gamma,
                                            const float* __restrict__ beta,
                                            float* __restrict__ z_full) {
  int bid = blockIdx.x;
  int tstep = bid >> 3;
  int z0 = (bid & 7) * 16;
  int tid = threadIdx.x;
  int zl = tid & 15, bg = tid >> 4;
  __shared__ float ps[256], qs[256];
  __shared__ float muS[16], rsS[16];
  float s = 0.f, ss = 0.f;
  for (int ii = 0; ii < 32; ++ii) {
    int b = bg * 32 + ii;
    float v = zbuf[(size_t)(b * 32 + tstep) * 128 + z0 + zl];
    s += v; ss += v * v;
  }
  ps[tid] = s; qs[tid] = ss;
  __syncthreads();
  if (tid < 16) {
    float S = 0.f, Q = 0.f;
    for (int g2 = 0; g2 < 16; ++g2) { S += ps[g2 * 16 + tid]; Q += qs[g2 * 16 + tid]; }
    float mu = S / 512.f;
    float var = Q / 512.f - mu * mu;
    muS[tid] = mu;
    rsS[tid] = rsqrtf(var + 1e-8f);
  }
  __syncthreads();
  float ga = gamma[z0 + zl], be = beta[z0 + zl];
  float mu = muS[zl], rs = rsS[zl];
  for (int ii = 0; ii < 32; ++ii) {
    int b = bg * 32 + ii;
    float v = zbuf[(size_t)(b * 32 + tstep) * 128 + z0 + zl];
    z_full[(size_t)(b * 33 + tstep) * 128 + z0 + zl] = (v - mu) * rs * ga + be;
  }
}

// ---------------------------------------------------------------------------
// Gates GEMM + fused LSTM cell. A = xin (512,800) bf16 = [key_r(257) pad(31) c(512)].
// B = WcombT (2048,800) bf16, rows permuted n' = j*4+gate. Block (nn,mi): 64x64
// tile -> 64 rows x 16 j's of the cell. Writes h (f32), hbf (bf16), c->xin_nxt.
// ---------------------------------------------------------------------------
__global__ __launch_bounds__(256) void k_gates(const unsigned short* __restrict__ xin,
                                               const unsigned short* __restrict__ WT,
                                               const float* __restrict__ b_lstm,
                                               float* __restrict__ h,
                                               unsigned short* __restrict__ hbf,
                                               unsigned short* __restrict__ xin_nxt) {
  __shared__ __align__(16) unsigned short As[64 * 32];
  __shared__ __align__(16) unsigned short Bs[64 * 32];
  __shared__ float Cs[64 * 65];
  int tid = threadIdx.x;
  int nn = blockIdx.x;          // 0..31  (16 j's each)
  int m0 = blockIdx.y * 64;     // 0..7
  int n0 = nn * 64;
  int lane = tid & 63, wid = tid >> 6;
  int wm = (wid >> 1) * 32, wn = (wid & 1) * 32;
  int q = lane >> 4, r = lane & 15;
  int ldrow = tid >> 2, ldc = (tid & 3) * 8;
  const uint4* Ag = reinterpret_cast<const uint4*>(xin + (size_t)(m0 + ldrow) * 800);
  const uint4* Bg = reinterpret_cast<const uint4*>(WT + (size_t)(n0 + ldrow) * 800);
  f32x4 acc[2][2] = {};
  for (int kk = 0; kk < 25; ++kk) {
    int k0 = kk * 32;
    *reinterpret_cast<uint4*>(&As[ldrow * 32 + ldc]) = Ag[(k0 + ldc) >> 3];
    *reinterpret_cast<uint4*>(&Bs[ldrow * 32 + ldc]) = Bg[(k0 + ldc) >> 3];
    __syncthreads();
    short8 a0 = *reinterpret_cast<const short8*>(&As[(wm + r) * 32 + q * 8]);
    short8 a1 = *reinterpret_cast<const short8*>(&As[(wm + 16 + r) * 32 + q * 8]);
    short8 b0 = *reinterpret_cast<const short8*>(&Bs[(wn + r) * 32 + q * 8]);
    short8 b1 = *reinterpret_cast<const short8*>(&Bs[(wn + 16 + r) * 32 + q * 8]);
    acc[0][0] = __builtin_amdgcn_mfma_f32_16x16x32_bf16(a0, b0, acc[0][0], 0, 0, 0);
    acc[0][1] = __builtin_amdgcn_mfma_f32_16x16x32_bf16(a0, b1, acc[0][1], 0, 0, 0);
    acc[1][0] = __builtin_amdgcn_mfma_f32_16x16x32_bf16(a1, b0, acc[1][0], 0, 0, 0);
    acc[1][1] = __builtin_amdgcn_mfma_f32_16x16x32_bf16(a1, b1, acc[1][1], 0, 0, 0);
    __syncthreads();
  }
  for (int mt = 0; mt < 2; ++mt)
    for (int nt = 0; nt < 2; ++nt)
      for (int e = 0; e < 4; ++e)
        Cs[(wm + mt * 16 + q * 4 + e) * 65 + wn + nt * 16 + r] = acc[mt][nt][e];
  __syncthreads();
  // cell: 64 rows x 16 j's, 4 per thread. local col = jl*4 + gate (i,f,g,o)
  for (int it = 0; it < 4; ++it) {
    int id = it * 256 + tid;
    int rl = id >> 4, jl = id & 15;
    int brow = m0 + rl;
    int j = nn * 16 + jl;
    float gi = Cs[rl * 65 + jl * 4 + 0] + b_lstm[j];
    float gf = Cs[rl * 65 + jl * 4 + 1] + b_lstm[512 + j];
    float gg = Cs[rl * 65 + jl * 4 + 2] + b_lstm[1024 + j];
    float go = Cs[rl * 65 + jl * 4 + 3] + b_lstm[1536 + j];
    float hold = h[brow * 512 + j];
    float cnew = sigm(gf) * hold + sigm(gi) * tanhf(gg);
    float hnew = sigm(go) * tanhf(cnew);
    h[brow * 512 + j] = hnew;
    hbf[brow * 512 + j] = f2bf(hnew);
    xin_nxt[brow * 800 + 288 + j] = f2bf(cnew);
  }
}

// ---------------------------------------------------------------------------
// Head: blocks 0..39 = GEMM2 (key_w -> M_k slot t, logits). Blocks 40..551 =
// per-batch attention read (g, sim, softmax, weighted) -> key_r into xin_nxt.
// ---------------------------------------------------------------------------
__global__ __launch_bounds__(256) void k_head(const unsigned short* __restrict__ hbf,
                                              const unsigned short* __restrict__ Wk2T,
                                              const float* __restrict__ bias2,
                                              float* __restrict__ Mk,
                                              float* __restrict__ logits,
                                              const float* __restrict__ z_full,
                                              const float* __restrict__ h,
                                              const float* __restrict__ Wg,
                                              const float* __restrict__ bg,
                                              const float* __restrict__ cgain,
                                              const float* __restrict__ cbias,
                                              unsigned short* __restrict__ xin_nxt,
                                              int t) {
  __shared__ __align__(16) unsigned short As[64 * 32];
  __shared__ __align__(16) unsigned short Bs[64 * 32];
  __shared__ float zt[128];
  __shared__ float simS[33];
  __shared__ float wkS[33];
  __shared__ float red[256];
  __shared__ float gS, wckS;
  int bid = blockIdx.x;
  int tid = threadIdx.x;
  if (bid < 40) {
    int mi = bid / 5, ni = bid - mi * 5;
    int m0 = mi * 64, n0 = ni * 64;
    int lane = tid & 63, wid = tid >> 6;
    int wm = (wid >> 1) * 32, wn = (wid & 1) * 32;
    int q = lane >> 4, r = lane & 15;
    int ldrow = tid >> 2, ldc = (tid & 3) * 8;
    const uint4* Ag = reinterpret_cast<const uint4*>(hbf + (size_t)(m0 + ldrow) * 512);
    const uint4* Bg = reinterpret_cast<const uint4*>(Wk2T + (size_t)(n0 + ldrow) * 512);
    f32x4 acc[2][2] = {};
    for (int kk = 0; kk < 16; ++kk) {
      int k0 = kk * 32;
      *reinterpret_cast<uint4*>(&As[ldrow * 32 + ldc]) = Ag[(k0 + ldc) >> 3];
      *reinterpret_cast<uint4*>(&Bs[ldrow * 32 + ldc]) = Bg[(k0 + ldc) >> 3];
      __syncthreads();
      short8 a0 = *reinterpret_cast<const short8*>(&As[(wm + r) * 32 + q * 8]);
      short8 a1 = *reinterpret_cast<const short8*>(&As[(wm + 16 + r) * 32 + q * 8]);
      short8 b0 = *reinterpret_cast<const short8*>(&Bs[(wn + r) * 32 + q * 8]);
      short8 b1 = *reinterpret_cast<const short8*>(&Bs[(wn + 16 + r) * 32 + q * 8]);
      acc[0][0] = __builtin_amdgcn_mfma_f32_16x16x32_bf16(a0, b0, acc[0][0], 0, 0, 0);
      acc[0][1] = __builtin_amdgcn_mfma_f32_16x16x32_bf16(a0, b1, acc[0][1], 0, 0, 0);
      acc[1][0] = __builtin_amdgcn_mfma_f32_16x16x32_bf16(a1, b0, acc[1][0], 0, 0, 0);
      acc[1][1] = __builtin_amdgcn_mfma_f32_16x16x32_bf16(a1, b1, acc[1][1], 0, 0, 0);
      __syncthreads();
    }
    for (int mt = 0; mt < 2; ++mt)
      for (int nt = 0; nt < 2; ++nt)
        for (int e = 0; e < 4; ++e) {
          int row = m0 + wm + mt * 16 + q * 4 + e;
          int np = n0 + wn + nt * 16 + r;
          float v = acc[mt][nt][e] + bias2[np];
          if (np < 256) Mk[(size_t)(row * 33 + t) * 256 + np] = fmaxf(v, 0.f);
          else if (np >= 257 && np < 261) logits[row * 4 + (np - 257)] = v;
        }
  } else {
    if (t == 0 || t == 32) return;  // key_r stays 0 at t=0; unused after t=32
    int b = bid - 40;
    const float* zb = z_full + (size_t)b * 33 * 128;
    if (tid < 128) zt[tid] = zb[t * 128 + tid];
    // g = sigmoid(h_new . W_g + b_g)
    float s = h[b * 512 + tid] * Wg[tid] + h[b * 512 + 256 + tid] * Wg[256 + tid];
    red[tid] = s;
    __syncthreads();
    for (int off = 128; off > 0; off >>= 1) {
      if (tid < off) red[tid] += red[tid + off];
      __syncthreads();
    }
    if (tid == 0) gS = 1.f / (1.f + __expf(-(red[0] + bg[0])));
    // sims over filled slots n < t
    int w = tid >> 6, l = tid & 63;
    for (int n = w; n < t; n += 4) {
      const float* zr = zb + n * 128;
      float p = zt[2 * l] * zr[2 * l] + zt[2 * l + 1] * zr[2 * l + 1];
      for (int off = 1; off < 64; off <<= 1) p += __shfl_xor(p, off);
      if (l == 0) simS[n] = p;
    }
    __syncthreads();
    if (tid < 64) {
      float v = (tid < t) ? simS[tid] : -3.0e38f;
      float m = v;
      for (int off = 1; off < 64; off <<= 1) m = fmaxf(m, __shfl_xor(m, off));
      float e = (tid < t) ? __expf(v - m) : 0.f;
      float ssum = e;
      for (int off = 1; off < 64; off <<= 1) ssum += __shfl_xor(ssum, off);
      float wk = e / ssum;
      if (tid < t) wkS[tid] = wk;
      float ck = (tid < t) ? 1.f / (1.f + __expf(-(simS[tid] * cgain[0] + cbias[0]))) : 0.f;
      float wc = wk * ck;
      for (int off = 1; off < 64; off <<= 1) wc += __shfl_xor(wc, off);
      if (tid == 0) wckS = wc;
    }
    __syncthreads();
    float acc = 0.f;
    for (int n = 0; n < t; ++n) acc += wkS[n] * Mk[(size_t)(b * 33 + n) * 256 + tid];
    float g = gS;
    xin_nxt[b * 800 + tid] = f2bf(g * acc);
    if (tid == 0) xin_nxt[b * 800 + 256] = f2bf(g * wckS);
  }
}

__global__ void k_softmax(const float* __restrict__ logits, float* __restrict__ out) {
  int tid = threadIdx.x;
  for (int r2 = tid; r2 < 512; r2 += 256) {
    float a = logits[r2 * 4], b = logits[r2 * 4 + 1], c = logits[r2 * 4 + 2], d = logits[r2 * 4 + 3];
    float m = fmaxf(fmaxf(a, b), fmaxf(c, d));
    float ea = __expf(a - m), eb = __expf(b - m), ec = __expf(c - m), ed = __expf(d - m);
    float s = ea + eb + ec + ed;
    out[r2 * 4] = ea / s; out[r2 * 4 + 1] = eb / s;
    out[r2 * 4 + 2] = ec / s; out[r2 * 4 + 3] = ed / s;
  }
}

extern "C" void kernel_launch(void* const* d_in, const int* in_sizes, int n_in,
                              void* d_out, int out_size, void* d_ws, size_t ws_size,
                              hipStream_t stream) {
  const float* x_seq = (const float*)d_in[0];
  const float* W_enc = (const float*)d_in[1];
  const float* b_enc = (const float*)d_in[2];
  const float* W_lstm = (const float*)d_in[3];
  const float* U_lstm = (const float*)d_in[4];
  const float* b_lstm = (const float*)d_in[5];
  const float* W_key = (const float*)d_in[6];
  const float* b_key = (const float*)d_in[7];
  const float* W_g = (const float*)d_in[8];
  const float* b_g = (const float*)d_in[9];
  const float* W_y = (const float*)d_in[10];
  const float* b_y = (const float*)d_in[11];
  const float* gamma = (const float*)d_in[12];
  const float* beta = (const float*)d_in[13];
  const float* cg = (const float*)d_in[14];
  const float* cb = (const float*)d_in[15];

  char* p = (char*)d_ws;
  auto alloc = [&](size_t bytes) {
    char* r = p;
    p += (bytes + 255) & ~(size_t)255;
    return r;
  };
  float* zbuf = (float*)alloc((size_t)16384 * 128 * 4);
  float* z_full = (float*)alloc((size_t)512 * 33 * 128 * 4);
  unsigned short* WcombT = (unsigned short*)alloc((size_t)2048 * 800 * 2);
  unsigned short* WencT = (unsigned short*)alloc((size_t)128 * 1024 * 2);
  unsigned short* Wk2T = (unsigned short*)alloc((size_t)320 * 512 * 2);
  float* bias2 = (float*)alloc(320 * 4);
  unsigned short* xinA = (unsigned short*)alloc((size_t)512 * 800 * 2);
  unsigned short* xinB = (unsigned short*)alloc((size_t)512 * 800 * 2);
  float* h = (float*)alloc((size_t)512 * 512 * 4);
  unsigned short* hbf = (unsigned short*)alloc((size_t)512 * 512 * 2);
  float* Mk = (float*)alloc((size_t)512 * 33 * 256 * 4);
  float* logits = (float*)alloc((size_t)512 * 4 * 4);

  const int prep_total = 2048 * 800 + 320 * 512 + 128 * 1024 + 320 + 2 * 512 * 800 + 512 * 512 + 512 * 128;
  k_prep<<<(prep_total + 255) / 256, 256, 0, stream>>>(
      W_lstm, U_lstm, W_enc, W_key, W_g, W_y, b_key, b_g, b_y,
      WcombT, Wk2T, WencT, bias2, xinA, xinB, h, z_full);
  k_enc<<<dim3(2, 256), 256, 0, stream>>>(x_seq, WencT, b_enc, zbuf);
  k_ln<<<256, 256, 0, stream>>>(zbuf, gamma, beta, z_full);
  for (int t = 0; t < 33; ++t) {
    unsigned short* cur = (t & 1) ? xinB : xinA;
    unsigned short* nxt = (t & 1) ? xinA : xinB;
    k_gates<<<dim3(32, 8), 256, 0, stream>>>(cur, WcombT, b_lstm, h, hbf, nxt);
    k_head<<<552, 256, 0, stream>>>(hbf, Wk2T, bias2, Mk, logits, z_full, h,
                                    W_g, b_g, cg, cb, nxt, t);
  }
  k_softmax<<<1, 256, 0, stream>>>(logits, (float*)d_out);
}

// Round 2
// 942.820 us; speedup vs baseline: 1.0885x; 1.0885x over previous
//
#include <hip/hip_runtime.h>

typedef __attribute__((ext_vector_type(8))) short short8;
typedef __attribute__((ext_vector_type(4))) float f32x4;
typedef __attribute__((ext_vector_type(8))) unsigned short ushort8;

__device__ __forceinline__ unsigned short f2bf(float f) {
  union { float f; unsigned u; } v; v.f = f;
  unsigned u = v.u;
  u += 0x7fffu + ((u >> 16) & 1u);
  return (unsigned short)(u >> 16);
}
__device__ __forceinline__ float sigm(float x) { return 1.f / (1.f + __expf(-x)); }
__device__ __forceinline__ float ftanh(float x) { return 1.f - 2.f / (__expf(2.f * x) + 1.f); }

#define LSTR 40  // LDS row stride (elems): 32 data + 8 pad -> rows advance 20 banks (2-way free)

// ---------------------------------------------------------------------------
// Prep: build bf16 transposed/permuted weights, zero state buffers.
// WcombT: (2048 rows n', 800 cols k) bf16. n' = j*4+gate  (orig col n = gate*512+j)
// Wk2T:   (320 rows n, 512 cols k) bf16. n<256->W_key, 256->W_g, 257..260->W_y
// WencT:  (128 rows n, 1024 cols k) bf16 = W_enc^T
// ---------------------------------------------------------------------------
__global__ void k_prep(const float* __restrict__ W_lstm, const float* __restrict__ U_lstm,
                       const float* __restrict__ W_enc, const float* __restrict__ W_key,
                       const float* __restrict__ W_g, const float* __restrict__ W_y,
                       const float* __restrict__ b_key, const float* __restrict__ b_g,
                       const float* __restrict__ b_y,
                       unsigned short* __restrict__ WcombT, unsigned short* __restrict__ Wk2T,
                       unsigned short* __restrict__ WencT, float* __restrict__ bias2,
                       unsigned short* __restrict__ xinA, unsigned short* __restrict__ xinB,
                       float* __restrict__ h, float* __restrict__ z_full) {
  const int N1 = 2048 * 800, N2 = 320 * 512, N3 = 128 * 1024, N4 = 320,
            N5 = 512 * 800, N7 = 512 * 512, N8 = 512 * 128;
  int i = blockIdx.x * 256 + threadIdx.x;
  if (i < N1) {
    int np = i / 800, k = i - np * 800;
    int j = np >> 2, gate = np & 3, n = gate * 512 + j;
    float v = 0.f;
    if (k < 257) v = W_lstm[k * 2048 + n];
    else if (k >= 288) v = U_lstm[(k - 288) * 2048 + n];
    WcombT[i] = f2bf(v);
    return;
  }
  i -= N1;
  if (i < N2) {
    int n = i / 512, k = i - n * 512;
    float v = 0.f;
    if (n < 256) v = W_key[k * 256 + n];
    else if (n == 256) v = W_g[k];
    else if (n < 261) v = W_y[k * 4 + (n - 257)];
    Wk2T[i] = f2bf(v);
    return;
  }
  i -= N2;
  if (i < N3) {
    int n = i / 1024, k = i - n * 1024;
    WencT[i] = f2bf(W_enc[k * 128 + n]);
    return;
  }
  i -= N3;
  if (i < N4) {
    float v = (i < 256) ? b_key[i] : (i == 256 ? b_g[0] : (i < 261 ? b_y[i - 257] : 0.f));
    bias2[i] = v;
    return;
  }
  i -= N4;
  if (i < N5) { xinA[i] = 0; return; }
  i -= N5;
  if (i < N5) { xinB[i] = 0; return; }
  i -= N5;
  if (i < N7) { h[i] = 0.f; return; }
  i -= N7;
  if (i < N8) {
    int b = i >> 7, z = i & 127;
    z_full[(b * 33 + 32) * 128 + z] = 0.f;  // null slot
  }
}

// ---------------------------------------------------------------------------
// Encoder GEMM: z = relu(x @ W_enc + b_enc). 64Mx128N tile per block, BK=32,
// K=1024, double-buffered LDS with register prefetch (1 sync/iter).
// ---------------------------------------------------------------------------
__global__ __launch_bounds__(256) void k_enc(const float* __restrict__ x,
                                             const unsigned short* __restrict__ WencT,
                                             const float* __restrict__ b_enc,
                                             float* __restrict__ zbuf) {
  __shared__ __align__(16) unsigned short As[2][64 * LSTR];
  __shared__ __align__(16) unsigned short Bs[2][128 * LSTR];
  int tid = threadIdx.x;
  int m0 = blockIdx.x * 64;
  int lane = tid & 63, wid = tid >> 6;
  int wm = (wid >> 1) * 32, wn = (wid & 1) * 64;
  int q = lane >> 4, r = lane & 15;
  int ldrowA = tid >> 2, ldcA = (tid & 3) * 8;
  int ldrowB = tid >> 1, ldcB = (tid & 1) * 16;
  const float4* Ag = reinterpret_cast<const float4*>(x + (size_t)(m0 + ldrowA) * 1024);
  const uint4* Bg = reinterpret_cast<const uint4*>(WencT + (size_t)ldrowB * 1024);
  float4 ra0 = Ag[ldcA >> 2], ra1 = Ag[(ldcA >> 2) + 1];
  uint4 rb0 = Bg[ldcB >> 3], rb1 = Bg[(ldcB >> 3) + 1];
  f32x4 acc[2][4] = {};
  int s = 0;
  {
    ushort8 t8;
    t8[0] = f2bf(ra0.x); t8[1] = f2bf(ra0.y); t8[2] = f2bf(ra0.z); t8[3] = f2bf(ra0.w);
    t8[4] = f2bf(ra1.x); t8[5] = f2bf(ra1.y); t8[6] = f2bf(ra1.z); t8[7] = f2bf(ra1.w);
    *reinterpret_cast<ushort8*>(&As[0][ldrowA * LSTR + ldcA]) = t8;
    *reinterpret_cast<uint4*>(&Bs[0][ldrowB * LSTR + ldcB]) = rb0;
    *reinterpret_cast<uint4*>(&Bs[0][ldrowB * LSTR + ldcB + 8]) = rb1;
  }
  __syncthreads();
  for (int kk = 0; kk < 32; ++kk) {
    if (kk < 31) {
      int k0 = (kk + 1) * 32;
      ra0 = Ag[(k0 + ldcA) >> 2]; ra1 = Ag[((k0 + ldcA) >> 2) + 1];
      rb0 = Bg[(k0 + ldcB) >> 3]; rb1 = Bg[((k0 + ldcB) >> 3) + 1];
    }
    short8 a0 = *reinterpret_cast<const short8*>(&As[s][(wm + r) * LSTR + q * 8]);
    short8 a1 = *reinterpret_cast<const short8*>(&As[s][(wm + 16 + r) * LSTR + q * 8]);
#pragma unroll
    for (int nt = 0; nt < 4; ++nt) {
      short8 b0 = *reinterpret_cast<const short8*>(&Bs[s][(wn + nt * 16 + r) * LSTR + q * 8]);
      acc[0][nt] = __builtin_amdgcn_mfma_f32_16x16x32_bf16(a0, b0, acc[0][nt], 0, 0, 0);
      acc[1][nt] = __builtin_amdgcn_mfma_f32_16x16x32_bf16(a1, b0, acc[1][nt], 0, 0, 0);
    }
    if (kk < 31) {
      ushort8 t8;
      t8[0] = f2bf(ra0.x); t8[1] = f2bf(ra0.y); t8[2] = f2bf(ra0.z); t8[3] = f2bf(ra0.w);
      t8[4] = f2bf(ra1.x); t8[5] = f2bf(ra1.y); t8[6] = f2bf(ra1.z); t8[7] = f2bf(ra1.w);
      *reinterpret_cast<ushort8*>(&As[s ^ 1][ldrowA * LSTR + ldcA]) = t8;
      *reinterpret_cast<uint4*>(&Bs[s ^ 1][ldrowB * LSTR + ldcB]) = rb0;
      *reinterpret_cast<uint4*>(&Bs[s ^ 1][ldrowB * LSTR + ldcB + 8]) = rb1;
      s ^= 1;
    }
    __syncthreads();
  }
#pragma unroll
  for (int mt = 0; mt < 2; ++mt)
#pragma unroll
    for (int nt = 0; nt < 4; ++nt)
#pragma unroll
      for (int e = 0; e < 4; ++e) {
        int row = m0 + wm + mt * 16 + q * 4 + e;
        int col = wn + nt * 16 + r;
        zbuf[(size_t)row * 128 + col] = fmaxf(acc[mt][nt][e] + b_enc[col], 0.f);
      }
}

// ---------------------------------------------------------------------------
// LayerNorm over the BATCH axis per (t,z).
// ---------------------------------------------------------------------------
__global__ __launch_bounds__(256) void k_ln(const float* __restrict__ zbuf,
                                            const float* __restrict__ gamma,
                                            const float* __restrict__ beta,
                                            float* __restrict__ z_full) {
  int bid = blockIdx.x;
  int tstep = bid >> 3;
  int z0 = (bid & 7) * 16;
  int tid = threadIdx.x;
  int zl = tid & 15, bg = tid >> 4;
  __shared__ float ps[256], qs[256];
  __shared__ float muS[16], rsS[16];
  float s = 0.f, ss = 0.f;
  for (int ii = 0; ii < 32; ++ii) {
    int b = bg * 32 + ii;
    float v = zbuf[(size_t)(b * 32 + tstep) * 128 + z0 + zl];
    s += v; ss += v * v;
  }
  ps[tid] = s; qs[tid] = ss;
  __syncthreads();
  if (tid < 16) {
    float S = 0.f, Q = 0.f;
    for (int g2 = 0; g2 < 16; ++g2) { S += ps[g2 * 16 + tid]; Q += qs[g2 * 16 + tid]; }
    float mu = S / 512.f;
    float var = Q / 512.f - mu * mu;
    muS[tid] = mu;
    rsS[tid] = rsqrtf(var + 1e-8f);
  }
  __syncthreads();
  float ga = gamma[z0 + zl], be = beta[z0 + zl];
  float mu = muS[zl], rs = rsS[zl];
  for (int ii = 0; ii < 32; ++ii) {
    int b = bg * 32 + ii;
    float v = zbuf[(size_t)(b * 32 + tstep) * 128 + z0 + zl];
    z_full[(size_t)(b * 33 + tstep) * 128 + z0 + zl] = (v - mu) * rs * ga + be;
  }
}

// ---------------------------------------------------------------------------
// Attention precompute: sim depends only on z_full, so w_k and wck = sum(wk*ck)
// for ALL t are computed once. Block = batch b.
// ---------------------------------------------------------------------------
__global__ __launch_bounds__(256) void k_attnpre(const float* __restrict__ z_full,
                                                 const float* __restrict__ cgain,
                                                 const float* __restrict__ cbias,
                                                 float* __restrict__ wk_tbl,
                                                 float* __restrict__ wck_tbl) {
  __shared__ float zs[33 * 128];
  __shared__ float sim[33 * 33];
  int b = blockIdx.x, tid = threadIdx.x;
  const float* zb = z_full + (size_t)b * 33 * 128;
  for (int i = tid; i < 33 * 128; i += 256) zs[i] = zb[i];
  __syncthreads();
  for (int p = tid; p < 33 * 33; p += 256) {
    int t = p / 33, n = p - t * 33;
    float s = 0.f;
    if (n < t) {
#pragma unroll 8
      for (int k2 = 0; k2 < 128; ++k2) s += zs[t * 128 + k2] * zs[n * 128 + k2];
    }
    sim[p] = s;
  }
  __syncthreads();
  if (tid >= 1 && tid < 33) {
    int t = tid;
    float cg = cgain[0], cb2 = cbias[0];
    float m = -3.0e38f;
    for (int n = 0; n < t; ++n) m = fmaxf(m, sim[t * 33 + n]);
    float ssum = 0.f;
    for (int n = 0; n < t; ++n) ssum += __expf(sim[t * 33 + n] - m);
    float inv = 1.f / ssum;
    float wck = 0.f;
    for (int n = 0; n < t; ++n) {
      float wk = __expf(sim[t * 33 + n] - m) * inv;
      wk_tbl[((size_t)b * 33 + t) * 33 + n] = wk;
      float ck = 1.f / (1.f + __expf(-(sim[t * 33 + n] * cg + cb2)));
      wck += wk * ck;
    }
    wck_tbl[b * 33 + t] = wck;
  }
}

// ---------------------------------------------------------------------------
// Gates GEMM + fused LSTM cell. A = xin (512,800) bf16 = [key_r(257) pad(31) c(512)].
// B = WcombT (2048,800), rows permuted n' = j*4+gate. Double-buffered, 1 sync/iter.
// ---------------------------------------------------------------------------
__global__ __launch_bounds__(256) void k_gates(const unsigned short* __restrict__ xin,
                                               const unsigned short* __restrict__ WT,
                                               const float* __restrict__ b_lstm,
                                               float* __restrict__ h,
                                               unsigned short* __restrict__ hbf,
                                               unsigned short* __restrict__ xin_nxt) {
  __shared__ __align__(16) unsigned short As[2][64 * LSTR];
  __shared__ __align__(16) unsigned short Bs[2][64 * LSTR];
  __shared__ float Cs[64 * 65];
  int tid = threadIdx.x;
  int nn = blockIdx.x;          // 0..31  (16 j's each)
  int m0 = blockIdx.y * 64;     // 0..7
  int n0 = nn * 64;
  int lane = tid & 63, wid = tid >> 6;
  int wm = (wid >> 1) * 32, wn = (wid & 1) * 32;
  int q = lane >> 4, r = lane & 15;
  int ldrow = tid >> 2, ldc = (tid & 3) * 8;
  const uint4* Ag = reinterpret_cast<const uint4*>(xin + (size_t)(m0 + ldrow) * 800);
  const uint4* Bg = reinterpret_cast<const uint4*>(WT + (size_t)(n0 + ldrow) * 800);
  uint4 ra = Ag[ldc >> 3], rb = Bg[ldc >> 3];
  f32x4 acc[2][2] = {};
  int s = 0;
  *reinterpret_cast<uint4*>(&As[0][ldrow * LSTR + ldc]) = ra;
  *reinterpret_cast<uint4*>(&Bs[0][ldrow * LSTR + ldc]) = rb;
  __syncthreads();
  for (int kk = 0; kk < 25; ++kk) {
    if (kk < 24) {
      int k0 = (kk + 1) * 32;
      ra = Ag[(k0 + ldc) >> 3];
      rb = Bg[(k0 + ldc) >> 3];
    }
    short8 a0 = *reinterpret_cast<const short8*>(&As[s][(wm + r) * LSTR + q * 8]);
    short8 a1 = *reinterpret_cast<const short8*>(&As[s][(wm + 16 + r) * LSTR + q * 8]);
    short8 b0 = *reinterpret_cast<const short8*>(&Bs[s][(wn + r) * LSTR + q * 8]);
    short8 b1 = *reinterpret_cast<const short8*>(&Bs[s][(wn + 16 + r) * LSTR + q * 8]);
    acc[0][0] = __builtin_amdgcn_mfma_f32_16x16x32_bf16(a0, b0, acc[0][0], 0, 0, 0);
    acc[0][1] = __builtin_amdgcn_mfma_f32_16x16x32_bf16(a0, b1, acc[0][1], 0, 0, 0);
    acc[1][0] = __builtin_amdgcn_mfma_f32_16x16x32_bf16(a1, b0, acc[1][0], 0, 0, 0);
    acc[1][1] = __builtin_amdgcn_mfma_f32_16x16x32_bf16(a1, b1, acc[1][1], 0, 0, 0);
    if (kk < 24) {
      *reinterpret_cast<uint4*>(&As[s ^ 1][ldrow * LSTR + ldc]) = ra;
      *reinterpret_cast<uint4*>(&Bs[s ^ 1][ldrow * LSTR + ldc]) = rb;
      s ^= 1;
    }
    __syncthreads();
  }
#pragma unroll
  for (int mt = 0; mt < 2; ++mt)
#pragma unroll
    for (int nt = 0; nt < 2; ++nt)
#pragma unroll
      for (int e = 0; e < 4; ++e)
        Cs[(wm + mt * 16 + q * 4 + e) * 65 + wn + nt * 16 + r] = acc[mt][nt][e];
  __syncthreads();
  // cell: 64 rows x 16 j's, 4 per thread. local col = jl*4 + gate (i,f,g,o)
#pragma unroll
  for (int it = 0; it < 4; ++it) {
    int id = it * 256 + tid;
    int rl = id >> 4, jl = id & 15;
    int brow = m0 + rl;
    int j = nn * 16 + jl;
    float gi = Cs[rl * 65 + jl * 4 + 0] + b_lstm[j];
    float gf = Cs[rl * 65 + jl * 4 + 1] + b_lstm[512 + j];
    float gg = Cs[rl * 65 + jl * 4 + 2] + b_lstm[1024 + j];
    float go = Cs[rl * 65 + jl * 4 + 3] + b_lstm[1536 + j];
    float hold = h[brow * 512 + j];
    float cnew = sigm(gf) * hold + sigm(gi) * ftanh(gg);
    float hnew = sigm(go) * ftanh(cnew);
    h[brow * 512 + j] = hnew;
    hbf[brow * 512 + j] = f2bf(hnew);
    xin_nxt[brow * 800 + 288 + j] = f2bf(cnew);
  }
}

// ---------------------------------------------------------------------------
// Head: blocks 0..39 = GEMM2 (key_w -> M_k slot t, logits), double-buffered.
// Blocks 40..551 = per-batch read: g (dot), weighted = sum wk*Mk -> key_r.
// ---------------------------------------------------------------------------
__global__ __launch_bounds__(256) void k_head(const unsigned short* __restrict__ hbf,
                                              const unsigned short* __restrict__ Wk2T,
                                              const float* __restrict__ bias2,
                                              float* __restrict__ Mk,
                                              float* __restrict__ logits,
                                              const float* __restrict__ h,
                                              const float* __restrict__ Wg,
                                              const float* __restrict__ bg,
                                              const float* __restrict__ wk_tbl,
                                              const float* __restrict__ wck_tbl,
                                              unsigned short* __restrict__ xin_nxt,
                                              int t) {
  __shared__ __align__(16) unsigned short As[2][64 * LSTR];
  __shared__ __align__(16) unsigned short Bs[2][64 * LSTR];
  __shared__ float wkS[33];
  __shared__ float red[256];
  int bid = blockIdx.x;
  int tid = threadIdx.x;
  if (bid < 40) {
    int mi = bid / 5, ni = bid - mi * 5;
    int m0 = mi * 64, n0 = ni * 64;
    int lane = tid & 63, wid = tid >> 6;
    int wm = (wid >> 1) * 32, wn = (wid & 1) * 32;
    int q = lane >> 4, r = lane & 15;
    int ldrow = tid >> 2, ldc = (tid & 3) * 8;
    const uint4* Ag = reinterpret_cast<const uint4*>(hbf + (size_t)(m0 + ldrow) * 512);
    const uint4* Bg = reinterpret_cast<const uint4*>(Wk2T + (size_t)(n0 + ldrow) * 512);
    uint4 ra = Ag[ldc >> 3], rb = Bg[ldc >> 3];
    f32x4 acc[2][2] = {};
    int s = 0;
    *reinterpret_cast<uint4*>(&As[0][ldrow * LSTR + ldc]) = ra;
    *reinterpret_cast<uint4*>(&Bs[0][ldrow * LSTR + ldc]) = rb;
    __syncthreads();
    for (int kk = 0; kk < 16; ++kk) {
      if (kk < 15) {
        int k0 = (kk + 1) * 32;
        ra = Ag[(k0 + ldc) >> 3];
        rb = Bg[(k0 + ldc) >> 3];
      }
      short8 a0 = *reinterpret_cast<const short8*>(&As[s][(wm + r) * LSTR + q * 8]);
      short8 a1 = *reinterpret_cast<const short8*>(&As[s][(wm + 16 + r) * LSTR + q * 8]);
      short8 b0 = *reinterpret_cast<const short8*>(&Bs[s][(wn + r) * LSTR + q * 8]);
      short8 b1 = *reinterpret_cast<const short8*>(&Bs[s][(wn + 16 + r) * LSTR + q * 8]);
      acc[0][0] = __builtin_amdgcn_mfma_f32_16x16x32_bf16(a0, b0, acc[0][0], 0, 0, 0);
      acc[0][1] = __builtin_amdgcn_mfma_f32_16x16x32_bf16(a0, b1, acc[0][1], 0, 0, 0);
      acc[1][0] = __builtin_amdgcn_mfma_f32_16x16x32_bf16(a1, b0, acc[1][0], 0, 0, 0);
      acc[1][1] = __builtin_amdgcn_mfma_f32_16x16x32_bf16(a1, b1, acc[1][1], 0, 0, 0);
      if (kk < 15) {
        *reinterpret_cast<uint4*>(&As[s ^ 1][ldrow * LSTR + ldc]) = ra;
        *reinterpret_cast<uint4*>(&Bs[s ^ 1][ldrow * LSTR + ldc]) = rb;
        s ^= 1;
      }
      __syncthreads();
    }
#pragma unroll
    for (int mt = 0; mt < 2; ++mt)
#pragma unroll
      for (int nt = 0; nt < 2; ++nt)
#pragma unroll
        for (int e = 0; e < 4; ++e) {
          int row = m0 + wm + mt * 16 + q * 4 + e;
          int np = n0 + wn + nt * 16 + r;
          float v = acc[mt][nt][e] + bias2[np];
          if (np < 256) Mk[(size_t)(row * 33 + t) * 256 + np] = fmaxf(v, 0.f);
          else if (np >= 257 && np < 261) logits[row * 4 + (np - 257)] = v;
        }
  } else {
    if (t == 0 || t == 32) return;  // key_r stays 0 at t=0; unused after t=32
    int b = bid - 40;
    float s = h[b * 512 + tid] * Wg[tid] + h[b * 512 + 256 + tid] * Wg[256 + tid];
    red[tid] = s;
    if (tid < t) wkS[tid] = wk_tbl[((size_t)b * 33 + t) * 33 + tid];
    __syncthreads();
    for (int off = 128; off > 0; off >>= 1) {
      if (tid < off) red[tid] += red[tid + off];
      __syncthreads();
    }
    float g = 1.f / (1.f + __expf(-(red[0] + bg[0])));
    float acc = 0.f;
    for (int n = 0; n < t; ++n) acc += wkS[n] * Mk[((size_t)b * 33 + n) * 256 + tid];
    xin_nxt[b * 800 + tid] = f2bf(g * acc);
    if (tid == 0) xin_nxt[b * 800 + 256] = f2bf(g * wck_tbl[b * 33 + t]);
  }
}

__global__ void k_softmax(const float* __restrict__ logits, float* __restrict__ out) {
  int tid = threadIdx.x;
  for (int r2 = tid; r2 < 512; r2 += 256) {
    float a = logits[r2 * 4], b = logits[r2 * 4 + 1], c = logits[r2 * 4 + 2], d = logits[r2 * 4 + 3];
    float m = fmaxf(fmaxf(a, b), fmaxf(c, d));
    float ea = __expf(a - m), eb = __expf(b - m), ec = __expf(c - m), ed = __expf(d - m);
    float s = ea + eb + ec + ed;
    out[r2 * 4] = ea / s; out[r2 * 4 + 1] = eb / s;
    out[r2 * 4 + 2] = ec / s; out[r2 * 4 + 3] = ed / s;
  }
}

extern "C" void kernel_launch(void* const* d_in, const int* in_sizes, int n_in,
                              void* d_out, int out_size, void* d_ws, size_t ws_size,
                              hipStream_t stream) {
  const float* x_seq = (const float*)d_in[0];
  const float* W_enc = (const float*)d_in[1];
  const float* b_enc = (const float*)d_in[2];
  const float* W_lstm = (const float*)d_in[3];
  const float* U_lstm = (const float*)d_in[4];
  const float* b_lstm = (const float*)d_in[5];
  const float* W_key = (const float*)d_in[6];
  const float* b_key = (const float*)d_in[7];
  const float* W_g = (const float*)d_in[8];
  const float* b_g = (const float*)d_in[9];
  const float* W_y = (const float*)d_in[10];
  const float* b_y = (const float*)d_in[11];
  const float* gamma = (const float*)d_in[12];
  const float* beta = (const float*)d_in[13];
  const float* cg = (const float*)d_in[14];
  const float* cb = (const float*)d_in[15];

  char* p = (char*)d_ws;
  auto alloc = [&](size_t bytes) {
    char* r = p;
    p += (bytes + 255) & ~(size_t)255;
    return r;
  };
  float* zbuf = (float*)alloc((size_t)16384 * 128 * 4);
  float* z_full = (float*)alloc((size_t)512 * 33 * 128 * 4);
  unsigned short* WcombT = (unsigned short*)alloc((size_t)2048 * 800 * 2);
  unsigned short* WencT = (unsigned short*)alloc((size_t)128 * 1024 * 2);
  unsigned short* Wk2T = (unsigned short*)alloc((size_t)320 * 512 * 2);
  float* bias2 = (float*)alloc(320 * 4);
  unsigned short* xinA = (unsigned short*)alloc((size_t)512 * 800 * 2);
  unsigned short* xinB = (unsigned short*)alloc((size_t)512 * 800 * 2);
  float* h = (float*)alloc((size_t)512 * 512 * 4);
  unsigned short* hbf = (unsigned short*)alloc((size_t)512 * 512 * 2);
  float* Mk = (float*)alloc((size_t)512 * 33 * 256 * 4);
  float* logits = (float*)alloc((size_t)512 * 4 * 4);
  float* wk_tbl = (float*)alloc((size_t)512 * 33 * 33 * 4);
  float* wck_tbl = (float*)alloc((size_t)512 * 33 * 4);

  const int prep_total = 2048 * 800 + 320 * 512 + 128 * 1024 + 320 + 2 * 512 * 800 + 512 * 512 + 512 * 128;
  k_prep<<<(prep_total + 255) / 256, 256, 0, stream>>>(
      W_lstm, U_lstm, W_enc, W_key, W_g, W_y, b_key, b_g, b_y,
      WcombT, Wk2T, WencT, bias2, xinA, xinB, h, z_full);
  k_enc<<<256, 256, 0, stream>>>(x_seq, WencT, b_enc, zbuf);
  k_ln<<<256, 256, 0, stream>>>(zbuf, gamma, beta, z_full);
  k_attnpre<<<512, 256, 0, stream>>>(z_full, cg, cb, wk_tbl, wck_tbl);
  for (int t = 0; t < 33; ++t) {
    unsigned short* cur = (t & 1) ? xinB : xinA;
    unsigned short* nxt = (t & 1) ? xinA : xinB;
    k_gates<<<dim3(32, 8), 256, 0, stream>>>(cur, WcombT, b_lstm, h, hbf, nxt);
    k_head<<<552, 256, 0, stream>>>(hbf, Wk2T, bias2, Mk, logits, h,
                                    W_g, b_g, wk_tbl, wck_tbl, nxt, t);
  }
  k_softmax<<<1, 256, 0, stream>>>(logits, (float*)d_out);
}